// Round 13
// baseline (127.936 us; speedup 1.0000x reference)
//
#include <hip/hip_runtime.h>
#include <hip/hip_cooperative_groups.h>

namespace cg = cooperative_groups;

// Problem constants (fixed by the reference)
#define BB 4
#define NN 50000
#define GG 2
#define EE 500000
#define HH 64
#define RR 16

// Fused-kernel geometry
#define GRID 256
#define THR  1024
#define TOTT (GRID * THR)                // 262144 threads
#define CVT  (GG * NN)                   // 100000 table rows
#define ZTOT (GG * NN + GG * BB * NN)    // s0g + s1g zero region

#define NTT   512                        // nodes per dst-tile
#define TILES 98                         // ceil(NN / NTT)
#define PBLK  128                        // edge-phase virtual blocks per graph
#define EPB   ((EE + PBLK - 1) / PBLK)   // 3907 edges per virtual block
#define CAP   96                         // records per (blk,tile); mean 40, +8.9 sigma; 384B = 6 lines

typedef float f32x2 __attribute__((ext_vector_type(2)));

// ---------------------------------------------------------------------------
// fp8 helpers (OCP e4m3, hw convert on gfx950)
// ---------------------------------------------------------------------------
__device__ inline unsigned int pack4_fp8(float f0, float f1, float f2, float f3) {
    int w = 0;
    w = __builtin_amdgcn_cvt_pk_fp8_f32(f0, f1, w, false);  // bytes 0,1
    w = __builtin_amdgcn_cvt_pk_fp8_f32(f2, f3, w, true);   // bytes 2,3
    return (unsigned int)w;
}

__device__ inline float dot16_fp8(uint4 a, uint4 b) {
    const unsigned int* pa = &a.x;
    const unsigned int* pb = &b.x;
    float s = 0.f;
#pragma unroll
    for (int i = 0; i < 4; ++i) {
        f32x2 al = __builtin_amdgcn_cvt_pk_f32_fp8((int)pa[i], false);
        f32x2 ah = __builtin_amdgcn_cvt_pk_f32_fp8((int)pa[i], true);
        f32x2 bl = __builtin_amdgcn_cvt_pk_f32_fp8((int)pb[i], false);
        f32x2 bh = __builtin_amdgcn_cvt_pk_f32_fp8((int)pb[i], true);
        s = fmaf(al.x, bl.x, s);
        s = fmaf(al.y, bl.y, s);
        s = fmaf(ah.x, bh.x, s);
        s = fmaf(ah.y, bh.y, s);
    }
    return s;
}

__device__ inline unsigned int f32_to_bf16_rn(float x) {
    unsigned int u = __float_as_uint(x);
    return (u + 0x7FFFu + ((u >> 16) & 1u)) >> 16;   // x >= 0, never NaN here
}

// ---------------------------------------------------------------------------
// ONE cooperative kernel, 3 phases separated by grid.sync():
//  A: fp8 table build (mask folded in u-row LSBs), pw/pb/wts, zero-init
//  B: per-edge gate -> packed records binned by dst-tile (LDS slot counters)
//  C: per-(tile,g) replay into LDS planes + fused ReLU-mean + out atomics
// ---------------------------------------------------------------------------
__global__ __launch_bounds__(THR) void fused_kernel(
    const float* __restrict__ pert_mask, const float* __restrict__ ctx,
    const int* __restrict__ esrc, const int* __restrict__ edst,
    const float* __restrict__ ewgt, const float* __restrict__ gu,
    const float* __restrict__ gv, const float* __restrict__ lin_w,
    const float* __restrict__ lin_b, const float* __restrict__ post_w,
    const float* __restrict__ post_b, const float* __restrict__ mix_w,
    const float* __restrict__ mix_b,
    uint4* __restrict__ guh, uint4* __restrict__ gvh,
    unsigned int* __restrict__ bins, int* __restrict__ counts,
    float* __restrict__ s0g, float* __restrict__ s1g,
    float* __restrict__ pw, float* __restrict__ pb, float* __restrict__ wts,
    float* __restrict__ out)
{
    cg::grid_group grid = cg::this_grid();
    int bid = blockIdx.x;
    int tid = threadIdx.x;
    int gt  = bid * THR + tid;

    __shared__ float ls[5][NTT];         // 10 KB (phase C planes; aliased in B)
    __shared__ int   lcnts[PBLK];        // 512 B (phase C counts)
    __shared__ float red[4][BB * HH];    // 4 KB  (phase C reduction)
    int* lcntB = (int*)ls;               // phase B per-tile slot counters

    // ======================= Phase A: prep =======================
    for (int i = gt; i < ZTOT; i += TOTT) s0g[i] = 0.f;
    if (gt < BB * HH) out[gt] = 0.f;

    if (gt < CVT) {                      // gt == g*NN + n
        int n = (gt >= NN) ? (gt - NN) : gt;
        const float4* us = (const float4*)(gu + (size_t)gt * RR);
        const float4* vs = (const float4*)(gv + (size_t)gt * RR);
        float4 a0 = us[0], a1 = us[1], a2 = us[2], a3 = us[3];
        uint4 ur;
        ur.x = pack4_fp8(a0.x, a0.y, a0.z, a0.w);
        ur.y = pack4_fp8(a1.x, a1.y, a1.z, a1.w);
        ur.z = pack4_fp8(a2.x, a2.y, a2.z, a2.w);
        ur.w = pack4_fp8(a3.x, a3.y, a3.z, a3.w);
        unsigned int mbits =
            ((pert_mask[0*NN + n] != 0.f) ? 0x1u        : 0u) |
            ((pert_mask[1*NN + n] != 0.f) ? 0x100u      : 0u) |
            ((pert_mask[2*NN + n] != 0.f) ? 0x10000u    : 0u) |
            ((pert_mask[3*NN + n] != 0.f) ? 0x1000000u  : 0u);
        ur.x = (ur.x & 0xFEFEFEFEu) | mbits;
        guh[gt] = ur;
        float4 b0 = vs[0], b1 = vs[1], b2 = vs[2], b3 = vs[3];
        uint4 vr;
        vr.x = pack4_fp8(b0.x, b0.y, b0.z, b0.w);
        vr.y = pack4_fp8(b1.x, b1.y, b1.z, b1.w);
        vr.z = pack4_fp8(b2.x, b2.y, b2.z, b2.w);
        vr.w = pack4_fp8(b3.x, b3.y, b3.z, b3.w);
        gvh[gt] = vr;
    }
    if (bid == 0) {
        if (tid < HH) {
            float a = 0.f, c = 0.f;
            for (int k = 0; k < HH; ++k) {
                float w = post_w[k*HH + tid];
                a = fmaf(lin_w[k], w, a);
                c = fmaf(lin_b[k], w, c);
            }
            pw[tid] = a; pb[tid] = c;
        } else if (tid < HH + BB) {
            int b = tid - HH;
            float l0 = mix_b[0], l1 = mix_b[1];
            for (int h = 0; h < HH; ++h) {
                float cv = ctx[b*HH + h];
                l0 = fmaf(cv, mix_w[h*GG + 0], l0);
                l1 = fmaf(cv, mix_w[h*GG + 1], l1);
            }
            float m = fmaxf(l0, l1);
            float e0 = __expf(l0 - m), e1 = __expf(l1 - m);
            float inv = 1.f / (e0 + e1);
            wts[b*GG + 0] = e0 * inv;
            wts[b*GG + 1] = e1 * inv;
        }
    }

    grid.sync();

    // ======================= Phase B: edge binning =======================
    {
        int g   = bid & 1;               // parity -> per-XCD graph affinity
        int blk = bid >> 1;              // 0..127
        if (tid < TILES) lcntB[tid] = 0;
        __syncthreads();

        int base   = blk * EPB;
        int nE     = min(EPB, EE - base);
        size_t gbase = (size_t)g * EE + base;
        int gN = g * NN;
        for (int it = tid; it < nE; it += 2 * THR) {
            int itB = it + THR;
            bool hB = itB < nE;
            int itBc = hB ? itB : it;    // clamp: loads unconditional
            int   sA = __builtin_nontemporal_load(esrc + gbase + it);
            int   dA = __builtin_nontemporal_load(edst + gbase + it);
            float wA = __builtin_nontemporal_load(ewgt + gbase + it);
            int   sB = __builtin_nontemporal_load(esrc + gbase + itBc);
            int   dB = __builtin_nontemporal_load(edst + gbase + itBc);
            float wB = __builtin_nontemporal_load(ewgt + gbase + itBc);
            uint4 uA = guh[gN + sA];
            uint4 vA = gvh[gN + dA];
            uint4 uB = guh[gN + sB];
            uint4 vB = gvh[gN + dB];
            // edge A
            {
                float dot = dot16_fp8(uA, vA);
                float w = wA / (1.f + __expf(-dot));
                unsigned int mb = (uA.x & 1u) | ((uA.x >> 7) & 2u) |
                                  ((uA.x >> 14) & 4u) | ((uA.x >> 21) & 8u);
                int tt = dA >> 9, dl = dA & (NTT - 1);
                int pos = atomicAdd(&lcntB[tt], 1);
                if (pos < CAP) {
                    bins[(((size_t)g * TILES + tt) * PBLK + blk) * CAP + pos] =
                        (f32_to_bf16_rn(w) << 16) | (mb << 9) | (unsigned)dl;
                } else {   // exact fallback (statistically never taken)
                    atomicAdd(&s0g[g * NN + dA], w);
                    if (mb & 1u) atomicAdd(&s1g[((size_t)g * BB + 0) * NN + dA], w);
                    if (mb & 2u) atomicAdd(&s1g[((size_t)g * BB + 1) * NN + dA], w);
                    if (mb & 4u) atomicAdd(&s1g[((size_t)g * BB + 2) * NN + dA], w);
                    if (mb & 8u) atomicAdd(&s1g[((size_t)g * BB + 3) * NN + dA], w);
                }
            }
            // edge B
            if (hB) {
                float dot = dot16_fp8(uB, vB);
                float w = wB / (1.f + __expf(-dot));
                unsigned int mb = (uB.x & 1u) | ((uB.x >> 7) & 2u) |
                                  ((uB.x >> 14) & 4u) | ((uB.x >> 21) & 8u);
                int tt = dB >> 9, dl = dB & (NTT - 1);
                int pos = atomicAdd(&lcntB[tt], 1);
                if (pos < CAP) {
                    bins[(((size_t)g * TILES + tt) * PBLK + blk) * CAP + pos] =
                        (f32_to_bf16_rn(w) << 16) | (mb << 9) | (unsigned)dl;
                } else {
                    atomicAdd(&s0g[g * NN + dB], w);
                    if (mb & 1u) atomicAdd(&s1g[((size_t)g * BB + 0) * NN + dB], w);
                    if (mb & 2u) atomicAdd(&s1g[((size_t)g * BB + 1) * NN + dB], w);
                    if (mb & 4u) atomicAdd(&s1g[((size_t)g * BB + 2) * NN + dB], w);
                    if (mb & 8u) atomicAdd(&s1g[((size_t)g * BB + 3) * NN + dB], w);
                }
            }
        }
        __syncthreads();
        if (tid < TILES)
            counts[((size_t)g * TILES + tid) * PBLK + blk] = min(lcntB[tid], CAP);
    }

    grid.sync();

    // ============== Phase C: tile replay + fused node reduction ==============
    if (bid < TILES * GG) {
        int g = bid & 1;
        int t = bid >> 1;
        int n0 = t * NTT;
        int ncnt = min(NTT, NN - n0);

        // seed planes from fallback accumulators (usually zeros)
        if (tid < NTT) {
            if (tid < ncnt) {
                ls[0][tid] = s0g[g * NN + n0 + tid];
#pragma unroll
                for (int b = 0; b < BB; ++b)
                    ls[1 + b][tid] = s1g[((size_t)g * BB + b) * NN + n0 + tid];
            } else {
                ls[0][tid] = 0.f; ls[1][tid] = 0.f; ls[2][tid] = 0.f;
                ls[3][tid] = 0.f; ls[4][tid] = 0.f;
            }
        }
        if (tid < PBLK)
            lcnts[tid] = counts[((size_t)g * TILES + t) * PBLK + tid];
        __syncthreads();

        // replay: 16 waves, 8 bins each
        int wv = tid >> 6, ln = tid & 63;
        const unsigned int* bbase = bins + ((size_t)g * TILES + t) * PBLK * CAP;
        for (int bI = wv; bI < PBLK; bI += THR / 64) {
            int cnt = lcnts[bI];
            const unsigned int* rp = bbase + (size_t)bI * CAP;
            for (int i = ln; i < cnt; i += 64) {
                unsigned int r = rp[i];
                float w = __uint_as_float(r & 0xFFFF0000u);
                int d = r & (NTT - 1);
                unsigned int mb = (r >> 9) & 15u;
                atomicAdd(&ls[0][d], w);
                if (mb & 1u) atomicAdd(&ls[1][d], w);
                if (mb & 2u) atomicAdd(&ls[2][d], w);
                if (mb & 4u) atomicAdd(&ls[3][d], w);
                if (mb & 8u) atomicAdd(&ls[4][d], w);
            }
        }
        __syncthreads();

        // fused relu + partial-mean: (b, sub) wave-groups, h = lane
        int b   = (tid >> 6) & 3;
        int sub = tid >> 8;              // 0..3
        int h   = tid & 63;
        float pwh = pw[h], pbh = pb[h], bias = post_b[h];
        float acc = 0.f;
        int i0 = sub * (NTT / 4);
        int i1 = min(i0 + (NTT / 4), ncnt);
        for (int i = i0; i < i1; ++i) {
            float x = fmaf(ls[1 + b][i], pwh, fmaf(ls[0][i], pbh, bias));
            acc += fmaxf(x, 0.f);
        }
        red[sub][b * HH + h] = acc;
        __syncthreads();
        if (tid < BB * HH) {
            float s = red[0][tid] + red[1][tid] + red[2][tid] + red[3][tid];
            int bb = tid >> 6;
            atomicAdd(&out[tid], s * wts[bb * GG + g] * (1.0f / NN));
        }
    }
}

// ---------------------------------------------------------------------------
extern "C" void kernel_launch(void* const* d_in, const int* in_sizes, int n_in,
                              void* d_out, int out_size, void* d_ws, size_t ws_size,
                              hipStream_t stream) {
    const float* pert_mask = (const float*)d_in[0];
    const float* ctx       = (const float*)d_in[1];
    const int*   esrc      = (const int*)d_in[2];
    const int*   edst      = (const int*)d_in[3];
    const float* ewgt      = (const float*)d_in[4];
    const float* gu        = (const float*)d_in[5];
    const float* gv        = (const float*)d_in[6];
    const float* lin_w     = (const float*)d_in[7];
    const float* lin_b     = (const float*)d_in[8];
    const float* post_w    = (const float*)d_in[9];
    const float* post_b    = (const float*)d_in[10];
    const float* mix_w     = (const float*)d_in[11];
    const float* mix_b     = (const float*)d_in[12];
    float* out = (float*)d_out;

    // workspace layout (float units)
    float* ws = (float*)d_ws;
    float* s0g = ws;                                   // 100,000 f
    float* s1g = ws + 100000;                          // 400,000 f (contig w/ s0g)
    uint4* guh = (uint4*)(ws + 500000);                // 100,000 uint4
    uint4* gvh = guh + 100000;                         // 100,000 uint4
    unsigned int* bins = (unsigned int*)(ws + 1300000);            // G*T*PBLK*CAP = 2,408,448 u32
    int* counts = (int*)(bins + (size_t)GG * TILES * PBLK * CAP);  // 25,088 int
    float* pw  = (float*)(counts + GG * TILES * PBLK); // 64 f
    float* pb  = pw + HH;                              // 64 f
    float* wts = pb + HH;                              // 8 f

    void* args[] = {
        (void*)&pert_mask, (void*)&ctx, (void*)&esrc, (void*)&edst,
        (void*)&ewgt, (void*)&gu, (void*)&gv, (void*)&lin_w, (void*)&lin_b,
        (void*)&post_w, (void*)&post_b, (void*)&mix_w, (void*)&mix_b,
        (void*)&guh, (void*)&gvh, (void*)&bins, (void*)&counts,
        (void*)&s0g, (void*)&s1g, (void*)&pw, (void*)&pb, (void*)&wts,
        (void*)&out
    };
    hipLaunchCooperativeKernel((void*)fused_kernel, dim3(GRID), dim3(THR),
                               args, 0, stream);
}

// Round 14
// 53.800 us; speedup vs baseline: 2.3780x; 2.3780x over previous
//
#include <hip/hip_runtime.h>

// Problem constants (fixed by the reference)
#define BB 4
#define NN 50000
#define GG 2
#define EE 500000
#define HH 64
#define RR 16

#define CVT (GG * NN)                    // one thread per (g,node): fp8 row packing
#define PREPB ((CVT + 255) / 256)        // 391 blocks
#define PREPT (PREPB * 256)              // 100,096 threads
#define ZTOT  (GG * NN + GG * BB * NN)   // s0g + s1g zero region

// Binning geometry
#define NTT   512                        // nodes per dst-tile
#define TILES 98                         // ceil(NN / NTT)
#define PBLK  128                        // pass-1 blocks per graph
#define EPB   ((EE + PBLK - 1) / PBLK)   // 3907 edges per pass-1 block
#define CAP   72                         // records per (block,tile); mean 40, +5 sigma

typedef float f32x2 __attribute__((ext_vector_type(2)));

// ---------------------------------------------------------------------------
// fp8 helpers (OCP e4m3, hw convert on gfx950)
// ---------------------------------------------------------------------------
__device__ inline unsigned int pack4_fp8(float f0, float f1, float f2, float f3) {
    int w = 0;
    w = __builtin_amdgcn_cvt_pk_fp8_f32(f0, f1, w, false);  // bytes 0,1
    w = __builtin_amdgcn_cvt_pk_fp8_f32(f2, f3, w, true);   // bytes 2,3
    return (unsigned int)w;
}

__device__ inline float dot16_fp8(uint4 a, uint4 b) {
    const unsigned int* pa = &a.x;
    const unsigned int* pb = &b.x;
    float s = 0.f;
#pragma unroll
    for (int i = 0; i < 4; ++i) {
        f32x2 al = __builtin_amdgcn_cvt_pk_f32_fp8((int)pa[i], false);
        f32x2 ah = __builtin_amdgcn_cvt_pk_f32_fp8((int)pa[i], true);
        f32x2 bl = __builtin_amdgcn_cvt_pk_f32_fp8((int)pb[i], false);
        f32x2 bh = __builtin_amdgcn_cvt_pk_f32_fp8((int)pb[i], true);
        s = fmaf(al.x, bl.x, s);
        s = fmaf(al.y, bl.y, s);
        s = fmaf(ah.x, bh.x, s);
        s = fmaf(ah.y, bh.y, s);
    }
    return s;
}

__device__ inline unsigned int f32_to_bf16_rn(float x) {
    unsigned int u = __float_as_uint(x);
    return (u + 0x7FFFu + ((u >> 16) & 1u)) >> 16;   // x >= 0, never NaN here
}

// ---------------------------------------------------------------------------
// Kernel A: prep — fp8 gate tables (16B/row, mask folded into u-row LSBs),
// pw/pb, softmax weights, zero-init via NT stores (no dirty L2 at boundary).
// ---------------------------------------------------------------------------
__global__ __launch_bounds__(256) void prep_kernel(
    const float* __restrict__ pert_mask, const float* __restrict__ ctx,
    const float* __restrict__ gu, const float* __restrict__ gv,
    const float* __restrict__ lin_w, const float* __restrict__ lin_b,
    const float* __restrict__ post_w, const float* __restrict__ mix_w,
    const float* __restrict__ mix_b,
    uint4* __restrict__ guh, uint4* __restrict__ gvh,
    float* __restrict__ pw, float* __restrict__ pb, float* __restrict__ wts,
    float* __restrict__ s0g /* s0g..s1g contiguous: ZTOT floats */,
    float* __restrict__ out)
{
    int t = blockIdx.x * 256 + threadIdx.x;
    // zero fallback planes (NT: dense, write-combining, no L2 dirtying)
    for (int i = t; i < ZTOT; i += PREPT)
        __builtin_nontemporal_store(0.f, &s0g[i]);
    if (t < BB * HH) out[t] = 0.f;

    if (t < CVT) {                       // t == g*NN + n
        int n = (t >= NN) ? (t - NN) : t;
        const float4* us = (const float4*)(gu + (size_t)t * RR);
        const float4* vs = (const float4*)(gv + (size_t)t * RR);
        float4 a0 = us[0], a1 = us[1], a2 = us[2], a3 = us[3];
        uint4 ur;
        ur.x = pack4_fp8(a0.x, a0.y, a0.z, a0.w);
        ur.y = pack4_fp8(a1.x, a1.y, a1.z, a1.w);
        ur.z = pack4_fp8(a2.x, a2.y, a2.z, a2.w);
        ur.w = pack4_fp8(a3.x, a3.y, a3.z, a3.w);
        // fold pert-mask bits into LSBs of bytes 0..3 (mask is src-indexed)
        unsigned int mbits =
            ((pert_mask[0*NN + n] != 0.f) ? 0x1u        : 0u) |
            ((pert_mask[1*NN + n] != 0.f) ? 0x100u      : 0u) |
            ((pert_mask[2*NN + n] != 0.f) ? 0x10000u    : 0u) |
            ((pert_mask[3*NN + n] != 0.f) ? 0x1000000u  : 0u);
        ur.x = (ur.x & 0xFEFEFEFEu) | mbits;
        guh[t] = ur;
        float4 b0 = vs[0], b1 = vs[1], b2 = vs[2], b3 = vs[3];
        uint4 vr;
        vr.x = pack4_fp8(b0.x, b0.y, b0.z, b0.w);
        vr.y = pack4_fp8(b1.x, b1.y, b1.z, b1.w);
        vr.z = pack4_fp8(b2.x, b2.y, b2.z, b2.w);
        vr.w = pack4_fp8(b3.x, b3.y, b3.z, b3.w);
        gvh[t] = vr;
    }
    if (blockIdx.x == 0) {
        int tt = threadIdx.x;
        if (tt < HH) {
            float a = 0.f, c = 0.f;
            for (int k = 0; k < HH; ++k) {
                float w = post_w[k*HH + tt];
                a = fmaf(lin_w[k], w, a);
                c = fmaf(lin_b[k], w, c);
            }
            pw[tt] = a; pb[tt] = c;
        } else if (tt < HH + BB) {
            int b = tt - HH;
            float l0 = mix_b[0], l1 = mix_b[1];
            for (int h = 0; h < HH; ++h) {
                float cv = ctx[b*HH + h];
                l0 = fmaf(cv, mix_w[h*GG + 0], l0);
                l1 = fmaf(cv, mix_w[h*GG + 1], l1);
            }
            float m = fmaxf(l0, l1);
            float e0 = __expf(l0 - m), e1 = __expf(l1 - m);
            float inv = 1.f / (e0 + e1);
            wts[b*GG + 0] = e0 * inv;
            wts[b*GG + 1] = e1 * inv;
        }
    }
}

// ---------------------------------------------------------------------------
// Pass 1: per-edge gate, emit packed record {bf16(w)<<16 | mask<<9 | dst_local}
// into bins[g][tile][blk][pos]. LDS slot counters; 2-wide pipeline; parity
// g = bid&1 keeps each XCD on one graph's L2-resident tables.
// ---------------------------------------------------------------------------
__device__ inline void emit_edge(
    uint4 ua, uint4 va, float w0, int d, int g,
    int* lcnt, unsigned int* __restrict__ bins, int blk,
    float* __restrict__ s0g, float* __restrict__ s1g)
{
    float dot = dot16_fp8(ua, va);
    float w = w0 / (1.f + __expf(-dot));    // weight * sigmoid(dot)
    unsigned int mb = (ua.x & 1u) | ((ua.x >> 7) & 2u) |
                      ((ua.x >> 14) & 4u) | ((ua.x >> 21) & 8u);
    int tt = d >> 9;               // dst tile (NTT = 512)
    int dl = d & (NTT - 1);        // local dst (9 bits)
    int pos = atomicAdd(&lcnt[tt], 1);
    if (pos < CAP) {
        unsigned int rec = (f32_to_bf16_rn(w) << 16) | (mb << 9) | (unsigned)dl;
        bins[(((size_t)g * TILES + tt) * PBLK + blk) * CAP + pos] = rec;
    } else {
        // exact fallback (statistically ~0 edges; keeps correctness)
        atomicAdd(&s0g[g * NN + d], w);
        if (mb & 1u) atomicAdd(&s1g[((size_t)g * BB + 0) * NN + d], w);
        if (mb & 2u) atomicAdd(&s1g[((size_t)g * BB + 1) * NN + d], w);
        if (mb & 4u) atomicAdd(&s1g[((size_t)g * BB + 2) * NN + d], w);
        if (mb & 8u) atomicAdd(&s1g[((size_t)g * BB + 3) * NN + d], w);
    }
}

__global__ __launch_bounds__(256) void edge_bin_kernel(
    const int* __restrict__ esrc, const int* __restrict__ edst,
    const float* __restrict__ ewgt, const uint4* __restrict__ guh,
    const uint4* __restrict__ gvh,
    unsigned int* __restrict__ bins, int* __restrict__ counts,
    float* __restrict__ s0g, float* __restrict__ s1g)
{
    int g   = blockIdx.x & 1;
    int blk = blockIdx.x >> 1;
    __shared__ int lcnt[TILES];
    int tid = threadIdx.x;
    if (tid < TILES) lcnt[tid] = 0;
    __syncthreads();

    int base   = blk * EPB;
    int nEdges = min(EPB, EE - base);
    size_t gbase = (size_t)g * EE + base;
    int gN = g * NN;
    for (int it = tid; it < nEdges; it += 512) {
        int itB = it + 256;
        bool hB = itB < nEdges;
        int itBc = hB ? itB : it;            // clamp: loads unconditional
        int   sA  = __builtin_nontemporal_load(esrc + gbase + it);
        int   dA  = __builtin_nontemporal_load(edst + gbase + it);
        float wA  = __builtin_nontemporal_load(ewgt + gbase + it);
        int   sB  = __builtin_nontemporal_load(esrc + gbase + itBc);
        int   dB  = __builtin_nontemporal_load(edst + gbase + itBc);
        float wB  = __builtin_nontemporal_load(ewgt + gbase + itBc);
        uint4 uA = guh[gN + sA];
        uint4 vA = gvh[gN + dA];
        uint4 uB = guh[gN + sB];
        uint4 vB = gvh[gN + dB];
        emit_edge(uA, vA, wA, dA, g, lcnt, bins, blk, s0g, s1g);
        if (hB) emit_edge(uB, vB, wB, dB, g, lcnt, bins, blk, s0g, s1g);
    }
    __syncthreads();
    if (tid < TILES)
        counts[((size_t)g * TILES + tid) * PBLK + blk] = min(lcnt[tid], CAP);
}

// ---------------------------------------------------------------------------
// Pass 2 (FUSED replay + node reduction): one block per (tile, graph),
// 1024 threads, 10 KB planes in LDS. All global reads non-temporal
// (read-once; no L2 pollution). 128 bins/tile at ~40 recs/bin.
// ---------------------------------------------------------------------------
#define P2T 1024

__global__ __launch_bounds__(P2T) void tile_node_kernel(
    const unsigned int* __restrict__ bins, const int* __restrict__ counts,
    const float* __restrict__ s0g, const float* __restrict__ s1g,
    const float* __restrict__ pw, const float* __restrict__ pb,
    const float* __restrict__ post_b, const float* __restrict__ wts,
    float* __restrict__ out)
{
    int t = blockIdx.x;      // tile
    int g = blockIdx.y;      // graph
    int n0 = t * NTT;
    int ncnt = min(NTT, NN - n0);
    __shared__ float ls[5][NTT];         // 10 KB
    __shared__ int   lcnts[PBLK];        // 512 B
    __shared__ float red[4][BB * HH];    // 4 KB
    int tid = threadIdx.x;

    // seed planes from fallback accumulators (usually zeros), NT loads
    if (tid < NTT) {
        if (tid < ncnt) {
            ls[0][tid] = __builtin_nontemporal_load(s0g + g * NN + n0 + tid);
#pragma unroll
            for (int b = 0; b < BB; ++b)
                ls[1 + b][tid] = __builtin_nontemporal_load(
                    s1g + ((size_t)g * BB + b) * NN + n0 + tid);
        } else {
            ls[0][tid] = 0.f; ls[1][tid] = 0.f; ls[2][tid] = 0.f;
            ls[3][tid] = 0.f; ls[4][tid] = 0.f;
        }
    }
    if (tid < PBLK)
        lcnts[tid] = __builtin_nontemporal_load(
            counts + ((size_t)g * TILES + t) * PBLK + tid);
    __syncthreads();

    // replay: 16 waves, 8 bins each (cnt ~40 -> one 64-lane pass/bin)
    int wv = tid >> 6, ln = tid & 63;
    const unsigned int* bbase = bins + ((size_t)g * TILES + t) * PBLK * CAP;
    for (int bI = wv; bI < PBLK; bI += P2T / 64) {
        int cnt = lcnts[bI];
        const unsigned int* rp = bbase + (size_t)bI * CAP;
        for (int i = ln; i < cnt; i += 64) {
            unsigned int r = __builtin_nontemporal_load(rp + i);
            float w = __uint_as_float(r & 0xFFFF0000u);
            int d = r & (NTT - 1);
            unsigned int mb = (r >> 9) & 15u;
            atomicAdd(&ls[0][d], w);
            if (mb & 1u) atomicAdd(&ls[1][d], w);
            if (mb & 2u) atomicAdd(&ls[2][d], w);
            if (mb & 4u) atomicAdd(&ls[3][d], w);
            if (mb & 8u) atomicAdd(&ls[4][d], w);
        }
    }
    __syncthreads();

    // fused relu + partial-mean: (b, sub) wave-groups, h = lane
    int b   = (tid >> 6) & 3;
    int sub = tid >> 8;                  // 0..3
    int h   = tid & 63;
    float pwh = pw[h], pbh = pb[h], bias = post_b[h];
    float acc = 0.f;
    int i0 = sub * (NTT / 4);
    int i1 = min(i0 + (NTT / 4), ncnt);
    for (int i = i0; i < i1; ++i) {
        float x = fmaf(ls[1 + b][i], pwh, fmaf(ls[0][i], pbh, bias));
        acc += fmaxf(x, 0.f);
    }
    red[sub][b * HH + h] = acc;
    __syncthreads();
    if (tid < BB * HH) {
        float s = red[0][tid] + red[1][tid] + red[2][tid] + red[3][tid];
        int bb = tid >> 6;
        atomicAdd(&out[tid], s * wts[bb * GG + g] * (1.0f / NN));
    }
}

// ---------------------------------------------------------------------------
extern "C" void kernel_launch(void* const* d_in, const int* in_sizes, int n_in,
                              void* d_out, int out_size, void* d_ws, size_t ws_size,
                              hipStream_t stream) {
    const float* pert_mask = (const float*)d_in[0];
    const float* ctx       = (const float*)d_in[1];
    const int*   esrc      = (const int*)d_in[2];
    const int*   edst      = (const int*)d_in[3];
    const float* ewgt      = (const float*)d_in[4];
    const float* gu        = (const float*)d_in[5];
    const float* gv        = (const float*)d_in[6];
    const float* lin_w     = (const float*)d_in[7];
    const float* lin_b     = (const float*)d_in[8];
    const float* post_w    = (const float*)d_in[9];
    const float* post_b    = (const float*)d_in[10];
    const float* mix_w     = (const float*)d_in[11];
    const float* mix_b     = (const float*)d_in[12];
    float* out = (float*)d_out;

    // workspace layout (float units)
    float* ws = (float*)d_ws;
    float* s0g = ws;                                   // 100,000 f
    float* s1g = ws + 100000;                          // 400,000 f (contig w/ s0g)
    uint4* guh = (uint4*)(ws + 500000);                // 100,000 uint4
    uint4* gvh = guh + 100000;                         // 100,000 uint4
    unsigned int* bins = (unsigned int*)(ws + 1300000);            // G*T*PBLK*CAP = 1,806,336 u32
    int* counts = (int*)(bins + (size_t)GG * TILES * PBLK * CAP);  // 25,088 int
    float* pw  = (float*)(counts + GG * TILES * PBLK); // 64 f
    float* pb  = pw + HH;                              // 64 f
    float* wts = pb + HH;                              // 8 f

    // NO hipMemsetAsync: prep_kernel zeroes s0g/s1g and out.

    prep_kernel<<<PREPB, 256, 0, stream>>>(
        pert_mask, ctx, gu, gv, lin_w, lin_b, post_w, mix_w, mix_b,
        guh, gvh, pw, pb, wts, s0g, out);

    edge_bin_kernel<<<2 * PBLK, 256, 0, stream>>>(
        esrc, edst, ewgt, guh, gvh, bins, counts, s0g, s1g);

    dim3 tg(TILES, GG);
    tile_node_kernel<<<tg, P2T, 0, stream>>>(
        bins, counts, s0g, s1g, pw, pb, post_b, wts, out);
}